// Round 1
// baseline (249.274 us; speedup 1.0000x reference)
//
#include <hip/hip_runtime.h>
#include <stdint.h>

// Problem constants
#define N_B 4
#define S_LEN 2048
#define N_W 8
#define N_H 8
#define D_HEAD 64
#define E_DIM 512

typedef __attribute__((ext_vector_type(8))) short bf16x8;
typedef __attribute__((ext_vector_type(4))) float f32x4;
typedef __attribute__((ext_vector_type(4))) unsigned int u32x4;
typedef __attribute__((ext_vector_type(4))) unsigned short u16x4;
typedef __attribute__((ext_vector_type(8))) unsigned short u16x8;

#define MFMA16(a, b, c) __builtin_amdgcn_mfma_f32_16x16x32_bf16((a), (b), (c), 0, 0, 0)

__device__ __forceinline__ unsigned short f2bf(float f) {
    union { float f; unsigned int u; } v; v.f = f;
    unsigned int r = v.u + 0x7fffu + ((v.u >> 16) & 1u);
    return (unsigned short)(r >> 16);
}

// ---------------------------------------------------------------------------
// Kernel 1: proj = cos(x + theta); Q,K row-major [BH][S][64] bf16 (Q * 1/8);
//           V transposed: Vt [BH][64][S] bf16.
// grid = B*S/32 = 256 blocks, 256 threads. Block handles 32 s-rows of one b.
// ---------------------------------------------------------------------------
__global__ __launch_bounds__(256) void qkv_kernel(
    const float* __restrict__ x, const float* __restrict__ theta,
    const float* __restrict__ Wq, const float* __restrict__ Wk,
    const float* __restrict__ Wv,
    unsigned short* __restrict__ Q, unsigned short* __restrict__ K,
    unsigned short* __restrict__ Vt)
{
    __shared__ float proj[32][9];  // pad to 9 floats to de-stride banks
    const int tid = threadIdx.x;
    const int row0 = blockIdx.x * 32;          // global row in [0, B*S)
    // phase 1: proj for this 32-row chunk (one cos per thread)
    {
        const int sl = tid >> 3, n = tid & 7;
        proj[sl][n] = cosf(x[row0 * 8 + tid] + theta[n]);
    }
    __syncthreads();
    const int b = row0 >> 11;          // row0 / S_LEN
    const int s_in_b = row0 & (S_LEN - 1);

    // phase 2: Q and K, coalesced-ish u16x4 stores
    {
        const int sl = tid >> 3, j0 = tid & 7;
        float pr[8];
        #pragma unroll
        for (int n = 0; n < 8; ++n) pr[n] = proj[sl][n];
        const int srow = s_in_b + sl;
        for (int jj = 0; jj < 16; ++jj) {
            const int combo = j0 + (jj << 3);      // 0..127
            const int h = combo >> 4;
            const int d0 = (combo & 15) << 2;
            const int e0 = h * 64 + d0;
            unsigned short oq[4], ok[4];
            #pragma unroll
            for (int i = 0; i < 4; ++i) {
                const float* wq = &Wq[(e0 + i) * 8];
                const float* wk = &Wk[(e0 + i) * 8];
                float aq = 0.f, ak = 0.f;
                #pragma unroll
                for (int n = 0; n < 8; ++n) {
                    aq += pr[n] * wq[n];
                    ak += pr[n] * wk[n];
                }
                oq[i] = f2bf(aq * 0.125f);   // fold 1/sqrt(d_k) into Q
                ok[i] = f2bf(ak);
            }
            const size_t base = ((size_t)(b * N_H + h) * S_LEN + srow) * 64 + d0;
            u16x4 vq = { oq[0], oq[1], oq[2], oq[3] };
            u16x4 vk = { ok[0], ok[1], ok[2], ok[3] };
            *(u16x4*)&Q[base] = vq;
            *(u16x4*)&K[base] = vk;
        }
    }

    // phase 3: V transposed. Thread t handles e = t, t+256; writes 32
    // contiguous s values per (h,d) row (64 B runs).
    for (int e = tid; e < E_DIM; e += 256) {
        const int h = e >> 6, d = e & 63;
        float wr[8];
        #pragma unroll
        for (int n = 0; n < 8; ++n) wr[n] = Wv[e * 8 + n];
        unsigned short* dst = &Vt[((size_t)(b * N_H + h) * 64 + d) * S_LEN + s_in_b];
        #pragma unroll
        for (int c = 0; c < 4; ++c) {
            u16x8 pk;
            #pragma unroll
            for (int k2 = 0; k2 < 8; ++k2) {
                const int sl = c * 8 + k2;
                float acc = 0.f;
                #pragma unroll
                for (int n = 0; n < 8; ++n) acc += proj[sl][n] * wr[n];
                pk[k2] = f2bf(acc);
            }
            *(u16x8*)&dst[c * 8] = pk;
        }
    }
}

// ---------------------------------------------------------------------------
// Kernel 2: flash attention. grid = B*H*16 = 512 blocks, 256 threads (4 waves).
// Block: q-tile of 128 rows for one (b,h). K-tiles of 128, online softmax.
// ---------------------------------------------------------------------------
__global__ __launch_bounds__(256, 2) void flash_kernel(
    const unsigned short* __restrict__ Q, const unsigned short* __restrict__ K,
    const unsigned short* __restrict__ Vt, unsigned short* __restrict__ O)
{
    __shared__ short kt[128 * 72];     // K-tile, row stride 72 elems (144 B)
    __shared__ short vt[64 * 136];     // Vt-tile, row stride 136 elems (272 B)
    __shared__ short pb[128 * 136];    // P buffer (wave-private row ranges)

    const int tid = threadIdx.x;
    const int lane = tid & 63, w = tid >> 6;
    const int quad = lane >> 4, lq = lane & 15;
    const int qt = blockIdx.x & 15, bh = blockIdx.x >> 4;
    const int b = bh >> 3, h = bh & 7;

    const unsigned short* Qb = Q + (size_t)bh * S_LEN * 64;
    const unsigned short* Kb = K + (size_t)bh * S_LEN * 64;
    const unsigned short* Vb = Vt + (size_t)bh * 64 * S_LEN;

    // Q fragments live in registers for the whole kernel.
    // A-layout: lane holds A[m = lane&15][k = quad*8 + j]
    bf16x8 qf[2][2];
    #pragma unroll
    for (int mt = 0; mt < 2; ++mt)
        #pragma unroll
        for (int ks = 0; ks < 2; ++ks)
            qf[mt][ks] = *(const bf16x8*)&Qb[(size_t)(qt * 128 + w * 32 + mt * 16 + lq) * 64 + ks * 32 + quad * 8];

    f32x4 oacc[2][4];
    #pragma unroll
    for (int mt = 0; mt < 2; ++mt)
        #pragma unroll
        for (int dt = 0; dt < 4; ++dt) oacc[mt][dt] = 0.f;
    float mst[2][4], lst[2][4];
    #pragma unroll
    for (int mt = 0; mt < 2; ++mt)
        #pragma unroll
        for (int r = 0; r < 4; ++r) { mst[mt][r] = -3.0e38f; lst[mt][r] = 0.f; }

    for (int kti = 0; kti < 16; ++kti) {
        const int kb = kti * 128;
        // stage K-tile: 128 rows x 64 cols bf16
        #pragma unroll
        for (int i = 0; i < 4; ++i) {
            const int u = tid + (i << 8);
            const int r = u >> 3, c = u & 7;
            *(u32x4*)&kt[r * 72 + c * 8] = *(const u32x4*)&Kb[(size_t)(kb + r) * 64 + c * 8];
        }
        // stage Vt-tile: 64 rows (d) x 128 cols (s)
        #pragma unroll
        for (int i = 0; i < 4; ++i) {
            const int u = tid + (i << 8);
            const int d = u >> 4, c = u & 15;
            *(u32x4*)&vt[d * 136 + c * 8] = *(const u32x4*)&Vb[(size_t)d * S_LEN + kb + c * 8];
        }
        __syncthreads();

        // scores S = Q . K^T  (B-operand from K rows: lane n=lq reads K[n][k])
        f32x4 sacc[2][8];
        #pragma unroll
        for (int mt = 0; mt < 2; ++mt)
            #pragma unroll
            for (int nt = 0; nt < 8; ++nt) sacc[mt][nt] = 0.f;
        #pragma unroll
        for (int nt = 0; nt < 8; ++nt) {
            #pragma unroll
            for (int ks = 0; ks < 2; ++ks) {
                bf16x8 bf = *(const bf16x8*)&kt[(nt * 16 + lq) * 72 + ks * 32 + quad * 8];
                #pragma unroll
                for (int mt = 0; mt < 2; ++mt)
                    sacc[mt][nt] = MFMA16(qf[mt][ks], bf, sacc[mt][nt]);
            }
        }

        // online softmax per row (rows live at quad*4+r; cols across lq + nt*16)
        #pragma unroll
        for (int mt = 0; mt < 2; ++mt) {
            #pragma unroll
            for (int r = 0; r < 4; ++r) {
                float mx = -3.0e38f;
                #pragma unroll
                for (int nt = 0; nt < 8; ++nt) mx = fmaxf(mx, sacc[mt][nt][r]);
                #pragma unroll
                for (int off = 1; off < 16; off <<= 1) mx = fmaxf(mx, __shfl_xor(mx, off));
                const float mo = mst[mt][r];
                const float mn = fmaxf(mo, mx);
                const float alpha = __expf(mo - mn);
                float rs = 0.f;
                #pragma unroll
                for (int nt = 0; nt < 8; ++nt) {
                    const float p = __expf(sacc[mt][nt][r] - mn);
                    sacc[mt][nt][r] = p;
                    rs += p;
                }
                #pragma unroll
                for (int off = 1; off < 16; off <<= 1) rs += __shfl_xor(rs, off);
                mst[mt][r] = mn;
                lst[mt][r] = lst[mt][r] * alpha + rs;
                #pragma unroll
                for (int dt = 0; dt < 4; ++dt) oacc[mt][dt][r] *= alpha;
                // write P (C-layout -> LDS) for the A-layout re-read below.
                const int prow = w * 32 + mt * 16 + quad * 4 + r;
                #pragma unroll
                for (int nt = 0; nt < 8; ++nt)
                    pb[prow * 136 + nt * 16 + lq] = (short)f2bf(sacc[mt][nt][r]);
            }
        }
        // P rows are wave-private: same-wave LDS write->read needs no barrier.

        // O += P . V   (A from pb, B from vt: lane d=lq reads Vt[d][n-run])
        #pragma unroll
        for (int ks = 0; ks < 4; ++ks) {
            bf16x8 af[2];
            #pragma unroll
            for (int mt = 0; mt < 2; ++mt)
                af[mt] = *(const bf16x8*)&pb[(w * 32 + mt * 16 + lq) * 136 + ks * 32 + quad * 8];
            #pragma unroll
            for (int dt = 0; dt < 4; ++dt) {
                bf16x8 bf = *(const bf16x8*)&vt[(dt * 16 + lq) * 136 + ks * 32 + quad * 8];
                #pragma unroll
                for (int mt = 0; mt < 2; ++mt)
                    oacc[mt][dt] = MFMA16(af[mt], bf, oacc[mt][dt]);
            }
        }
        __syncthreads();  // protect kt/vt before next stage
    }

    // epilogue: normalize and store O[b][s][h*64+d] bf16
    #pragma unroll
    for (int mt = 0; mt < 2; ++mt) {
        #pragma unroll
        for (int r = 0; r < 4; ++r) {
            const float inv = 1.0f / lst[mt][r];
            const int row = qt * 128 + w * 32 + mt * 16 + quad * 4 + r;
            unsigned short* dst = &O[((size_t)b * S_LEN + row) * E_DIM + h * 64];
            #pragma unroll
            for (int dt = 0; dt < 4; ++dt)
                dst[dt * 16 + lq] = f2bf(oacc[mt][dt][r] * inv);
        }
    }
}

// ---------------------------------------------------------------------------
// Kernel 3: Y[m][f] = sum_e O[m][e] * Wc[f][e].  M=8192, N=512, K=512.
// 128x128 tiles, Wc cast fp32->bf16 during staging. grid = 64*4 = 256 blocks.
// ---------------------------------------------------------------------------
__global__ __launch_bounds__(256, 2) void outproj_kernel(
    const unsigned short* __restrict__ O, const float* __restrict__ Wc,
    float* __restrict__ Y)
{
    __shared__ short at[128 * 72];
    __shared__ short bt[128 * 72];
    const int tid = threadIdx.x;
    const int lane = tid & 63, w = tid >> 6;
    const int quad = lane >> 4, lq = lane & 15;
    const int m0 = (blockIdx.x >> 2) * 128;
    const int f0 = (blockIdx.x & 3) * 128;

    f32x4 acc[2][8];
    #pragma unroll
    for (int mt = 0; mt < 2; ++mt)
        #pragma unroll
        for (int nt = 0; nt < 8; ++nt) acc[mt][nt] = 0.f;

    for (int e0 = 0; e0 < E_DIM; e0 += 64) {
        // A-tile: O rows, bf16 already
        #pragma unroll
        for (int i = 0; i < 4; ++i) {
            const int u = tid + (i << 8);
            const int r = u >> 3, c = u & 7;
            *(u32x4*)&at[r * 72 + c * 8] = *(const u32x4*)&O[(size_t)(m0 + r) * E_DIM + e0 + c * 8];
        }
        // B-tile: Wc rows f0..f0+127, cast fp32 -> bf16
        #pragma unroll
        for (int i = 0; i < 8; ++i) {
            const int u = tid + (i << 8);
            const int r = u >> 4, c = u & 15;
            f32x4 fv = *(const f32x4*)&Wc[(size_t)(f0 + r) * E_DIM + e0 + c * 4];
            u16x4 pk = { f2bf(fv[0]), f2bf(fv[1]), f2bf(fv[2]), f2bf(fv[3]) };
            *(u16x4*)&bt[r * 72 + c * 4] = pk;
        }
        __syncthreads();
        #pragma unroll
        for (int ks = 0; ks < 2; ++ks) {
            bf16x8 af[2];
            #pragma unroll
            for (int mt = 0; mt < 2; ++mt)
                af[mt] = *(const bf16x8*)&at[(w * 32 + mt * 16 + lq) * 72 + ks * 32 + quad * 8];
            #pragma unroll
            for (int nt = 0; nt < 8; ++nt) {
                bf16x8 bf = *(const bf16x8*)&bt[(nt * 16 + lq) * 72 + ks * 32 + quad * 8];
                #pragma unroll
                for (int mt = 0; mt < 2; ++mt)
                    acc[mt][nt] = MFMA16(af[mt], bf, acc[mt][nt]);
            }
        }
        __syncthreads();
    }

    #pragma unroll
    for (int mt = 0; mt < 2; ++mt)
        #pragma unroll
        for (int nt = 0; nt < 8; ++nt)
            #pragma unroll
            for (int r = 0; r < 4; ++r)
                Y[(size_t)(m0 + w * 32 + mt * 16 + quad * 4 + r) * E_DIM + f0 + nt * 16 + lq] = acc[mt][nt][r];
}

// ---------------------------------------------------------------------------
extern "C" void kernel_launch(void* const* d_in, const int* in_sizes, int n_in,
                              void* d_out, int out_size, void* d_ws, size_t ws_size,
                              hipStream_t stream) {
    const float* x     = (const float*)d_in[0];
    const float* theta = (const float*)d_in[1];
    const float* Wq    = (const float*)d_in[2];
    const float* Wk    = (const float*)d_in[3];
    const float* Wv    = (const float*)d_in[4];
    const float* Wc    = (const float*)d_in[5];
    float* Y = (float*)d_out;

    char* ws = (char*)d_ws;
    unsigned short* Q  = (unsigned short*)(ws);                      // 8 MB
    unsigned short* K  = (unsigned short*)(ws + ((size_t)8 << 20));  // 8 MB
    unsigned short* Vt = (unsigned short*)(ws + ((size_t)16 << 20)); // 8 MB
    unsigned short* O  = (unsigned short*)(ws + ((size_t)24 << 20)); // 8 MB

    qkv_kernel<<<(N_B * S_LEN) / 32, 256, 0, stream>>>(x, theta, Wq, Wk, Wv, Q, K, Vt);
    flash_kernel<<<N_B * N_H * (S_LEN / 128), 256, 0, stream>>>(Q, K, Vt, O);
    outproj_kernel<<<(N_B * S_LEN / 128) * (E_DIM / 128), 256, 0, stream>>>(O, Wc, Y);
}

// Round 2
// 145.984 us; speedup vs baseline: 1.7075x; 1.7075x over previous
//
#include <hip/hip_runtime.h>
#include <stdint.h>

#define N_B 4
#define S_LEN 2048
#define N_H 8
#define E_DIM 512

typedef __attribute__((ext_vector_type(8))) short bf16x8;
typedef __attribute__((ext_vector_type(4))) float f32x4;
typedef __attribute__((ext_vector_type(4))) unsigned int u32x4;
typedef __attribute__((ext_vector_type(2))) unsigned int u32x2;
typedef __attribute__((ext_vector_type(4))) unsigned short u16x4;
typedef __attribute__((ext_vector_type(8))) unsigned short u16x8;

#define MFMA16(a, b, c) __builtin_amdgcn_mfma_f32_16x16x32_bf16((a), (b), (c), 0, 0, 0)

__device__ __forceinline__ unsigned short f2bf(float f) {
    union { float f; unsigned int u; } v; v.f = f;
    unsigned int r = v.u + 0x7fffu + ((v.u >> 16) & 1u);
    return (unsigned short)(r >> 16);
}

// pack two f32 -> two bf16 (round-half-up) in one u32 via v_perm
__device__ __forceinline__ unsigned int pack2bf(float lo, float hi) {
    union { float f; unsigned int u; } a, b; a.f = lo; b.f = hi;
    return __builtin_amdgcn_perm(b.u + 0x8000u, a.u + 0x8000u, 0x07060302u);
}

__device__ __forceinline__ float fexp2(float x) {
#if __has_builtin(__builtin_amdgcn_exp2f)
    return __builtin_amdgcn_exp2f(x);
#else
    return exp2f(x);
#endif
}

// Q pre-scale: 1/sqrt(64) * log2(e)  (scores land in log2 domain)
#define Q_SCALE 0.18033688f

// ---------------------------------------------------------------------------
// Kernel 1: proj = cos(x+theta); Q,K row-major [BH][S][64] bf16 (Q*Q_SCALE);
//           Vt [BH][64][S] bf16.  grid = 256 chunks x 3 mats = 768 blocks.
// ---------------------------------------------------------------------------
__global__ __launch_bounds__(256) void qkv_kernel(
    const float* __restrict__ x, const float* __restrict__ theta,
    const float* __restrict__ Wq, const float* __restrict__ Wk,
    const float* __restrict__ Wv,
    unsigned short* __restrict__ Q, unsigned short* __restrict__ K,
    unsigned short* __restrict__ Vt)
{
    __shared__ float proj[32][8];
    const int tid = threadIdx.x;
    const int mat = blockIdx.x % 3;
    const int chunk = blockIdx.x / 3;
    const int row0 = chunk * 32;
    const int b = row0 >> 11;
    const int s_in_b = row0 & (S_LEN - 1);

    proj[tid >> 3][tid & 7] = cosf(x[row0 * 8 + tid] + theta[tid & 7]);
    __syncthreads();

    if (mat < 2) {
        const float* W = (mat == 0) ? Wq : Wk;
        const float scale = (mat == 0) ? Q_SCALE : 1.0f;
        unsigned short* outp = (mat == 0) ? Q : K;
        float w0[8], w1[8];
        #pragma unroll
        for (int n = 0; n < 8; ++n) {
            w0[n] = W[tid * 8 + n] * scale;
            w1[n] = W[(tid + 256) * 8 + n] * scale;
        }
        const int h0 = tid >> 6, h1 = (tid + 256) >> 6, d = tid & 63;
        unsigned short* p0 = outp + ((size_t)(b * N_H + h0) * S_LEN + s_in_b) * 64 + d;
        unsigned short* p1 = outp + ((size_t)(b * N_H + h1) * S_LEN + s_in_b) * 64 + d;
        #pragma unroll 4
        for (int s = 0; s < 32; ++s) {
            f32x4 pa = *(const f32x4*)&proj[s][0];
            f32x4 pc = *(const f32x4*)&proj[s][4];
            float a0 = 0.f, a1 = 0.f;
            #pragma unroll
            for (int n = 0; n < 4; ++n) {
                a0 += pa[n] * w0[n] + pc[n] * w0[n + 4];
                a1 += pa[n] * w1[n] + pc[n] * w1[n + 4];
            }
            p0[s * 64] = f2bf(a0);
            p1[s * 64] = f2bf(a1);
        }
    } else {
        // Vt: quad of 4 lanes per d-column; lane handles 8 s-values -> u16x8.
        // 8 passes of 64 e-columns.
        f32x4 ps[8][2];
        const int sl0 = (tid & 3) * 8;
        #pragma unroll
        for (int k2 = 0; k2 < 8; ++k2) {
            ps[k2][0] = *(const f32x4*)&proj[sl0 + k2][0];
            ps[k2][1] = *(const f32x4*)&proj[sl0 + k2][4];
        }
        const int ecol = tid >> 2;   // 0..63
        for (int pass = 0; pass < 8; ++pass) {
            const int e = pass * 64 + ecol;
            const int h = e >> 6, dd = e & 63;
            float wr[8];
            #pragma unroll
            for (int n = 0; n < 8; ++n) wr[n] = Wv[e * 8 + n];
            u16x8 pk;
            #pragma unroll
            for (int k2 = 0; k2 < 8; ++k2) {
                float acc = 0.f;
                #pragma unroll
                for (int n = 0; n < 4; ++n)
                    acc += ps[k2][0][n] * wr[n] + ps[k2][1][n] * wr[n + 4];
                pk[k2] = f2bf(acc);
            }
            *(u16x8*)&Vt[((size_t)(b * N_H + h) * 64 + dd) * S_LEN + s_in_b + sl0] = pk;
        }
    }
}

// ---------------------------------------------------------------------------
// Kernel 2: flash attention, S^T formulation. grid = 512 blocks, 256 threads.
// S^T = K.Q^T (C-layout: lane holds q=lq, k=quad*4+r) -> in-lane softmax,
// b64 P-writes, PV as before. Register double-buffer for K/V staging.
// ---------------------------------------------------------------------------
__global__ __launch_bounds__(256, 2) void flash_kernel(
    const unsigned short* __restrict__ Q, const unsigned short* __restrict__ K,
    const unsigned short* __restrict__ Vt, unsigned short* __restrict__ O)
{
    __shared__ short kt[128 * 72];
    __shared__ short vt[64 * 136];
    __shared__ short pb[128 * 136];

    const int tid = threadIdx.x;
    const int lane = tid & 63, w = tid >> 6;
    const int quad = lane >> 4, lq = lane & 15;
    const int qt = blockIdx.x & 15, bh = blockIdx.x >> 4;
    const int b = bh >> 3, h = bh & 7;

    const unsigned short* Qb = Q + (size_t)bh * S_LEN * 64;
    const unsigned short* Kb = K + (size_t)bh * S_LEN * 64;
    const unsigned short* Vb = Vt + (size_t)bh * 64 * S_LEN;

    // Q fragments (used as MFMA B-operand): lane holds Q[q=lq][d=quad*8+j]
    bf16x8 qf[2][2];
    #pragma unroll
    for (int mt = 0; mt < 2; ++mt)
        #pragma unroll
        for (int ks = 0; ks < 2; ++ks)
            qf[mt][ks] = *(const bf16x8*)&Qb[(size_t)(qt * 128 + w * 32 + mt * 16 + lq) * 64 + ks * 32 + quad * 8];

    f32x4 oacc[2][4];
    #pragma unroll
    for (int mt = 0; mt < 2; ++mt)
        #pragma unroll
        for (int dt = 0; dt < 4; ++dt) oacc[mt][dt] = 0.f;
    float mst[2] = {-3.0e38f, -3.0e38f};
    float lst[2] = {0.f, 0.f};

    // preload tile 0 into regs
    u32x4 pkr[4], pvr[4];
    #pragma unroll
    for (int i = 0; i < 4; ++i) {
        const int u = tid + (i << 8);
        pkr[i] = *(const u32x4*)&Kb[(size_t)(u >> 3) * 64 + (u & 7) * 8];
        pvr[i] = *(const u32x4*)&Vb[(size_t)(u >> 4) * S_LEN + (u & 15) * 8];
    }

    for (int kti = 0; kti < 16; ++kti) {
        __syncthreads();   // prior tile's LDS reads complete
        #pragma unroll
        for (int i = 0; i < 4; ++i) {
            const int u = tid + (i << 8);
            *(u32x4*)&kt[(u >> 3) * 72 + (u & 7) * 8] = pkr[i];
            *(u32x4*)&vt[(u >> 4) * 136 + (u & 15) * 8] = pvr[i];
        }
        __syncthreads();

        // prefetch next tile (dummy tile 0 on last iter)
        const int kb2 = (kti < 15) ? (kti + 1) * 128 : 0;
        #pragma unroll
        for (int i = 0; i < 4; ++i) {
            const int u = tid + (i << 8);
            pkr[i] = *(const u32x4*)&Kb[(size_t)(kb2 + (u >> 3)) * 64 + (u & 7) * 8];
            pvr[i] = *(const u32x4*)&Vb[(size_t)(u >> 4) * S_LEN + kb2 + (u & 15) * 8];
        }

        // S^T = K . Q^T : sacc[mt][mts], rows = k, cols = q
        f32x4 sacc[2][8];
        #pragma unroll
        for (int mt = 0; mt < 2; ++mt)
            #pragma unroll
            for (int mts = 0; mts < 8; ++mts) sacc[mt][mts] = 0.f;
        #pragma unroll
        for (int mts = 0; mts < 8; ++mts) {
            #pragma unroll
            for (int ks = 0; ks < 2; ++ks) {
                bf16x8 af = *(const bf16x8*)&kt[(mts * 16 + lq) * 72 + ks * 32 + quad * 8];
                sacc[0][mts] = MFMA16(af, qf[0][ks], sacc[0][mts]);
                sacc[1][mts] = MFMA16(af, qf[1][ks], sacc[1][mts]);
            }
        }

        // online softmax: per-lane state is for q = lq (replicated over quads)
        #pragma unroll
        for (int mt = 0; mt < 2; ++mt) {
            f32x4 vmax = sacc[mt][0];
            #pragma unroll
            for (int mts = 1; mts < 8; ++mts) {
                #pragma unroll
                for (int e = 0; e < 4; ++e) vmax[e] = fmaxf(vmax[e], sacc[mt][mts][e]);
            }
            float mx = fmaxf(fmaxf(vmax[0], vmax[1]), fmaxf(vmax[2], vmax[3]));
            mx = fmaxf(mx, __shfl_xor(mx, 16));
            mx = fmaxf(mx, __shfl_xor(mx, 32));
            const float mo = mst[mt];
            const float mn = fmaxf(mo, mx);
            const float alpha = fexp2(mo - mn);
            f32x4 vsum = 0.f;
            #pragma unroll
            for (int mts = 0; mts < 8; ++mts) {
                f32x4 p;
                #pragma unroll
                for (int e = 0; e < 4; ++e) p[e] = fexp2(sacc[mt][mts][e] - mn);
                vsum += p;
                u32x2 pw = { pack2bf(p[0], p[1]), pack2bf(p[2], p[3]) };
                *(u32x2*)&pb[(w * 32 + mt * 16 + lq) * 136 + mts * 16 + quad * 4] = pw;
            }
            float rs = (vsum[0] + vsum[1]) + (vsum[2] + vsum[3]);
            rs += __shfl_xor(rs, 16);
            rs += __shfl_xor(rs, 32);
            lst[mt] = lst[mt] * alpha + rs;
            mst[mt] = mn;
            // rescale O accumulator (rows quad*4+r need alpha of q=quad*4+r)
            #pragma unroll
            for (int r = 0; r < 4; ++r) {
                const float ar = __shfl(alpha, quad * 4 + r);
                #pragma unroll
                for (int dt = 0; dt < 4; ++dt) oacc[mt][dt][r] *= ar;
            }
        }
        // pb rows are wave-private: no barrier needed between write and read.

        // O += P . V
        #pragma unroll
        for (int ks = 0; ks < 4; ++ks) {
            bf16x8 af0 = *(const bf16x8*)&pb[(w * 32 + lq) * 136 + ks * 32 + quad * 8];
            bf16x8 af1 = *(const bf16x8*)&pb[(w * 32 + 16 + lq) * 136 + ks * 32 + quad * 8];
            #pragma unroll
            for (int dt = 0; dt < 4; ++dt) {
                bf16x8 bf = *(const bf16x8*)&vt[(dt * 16 + lq) * 136 + ks * 32 + quad * 8];
                oacc[0][dt] = MFMA16(af0, bf, oacc[0][dt]);
                oacc[1][dt] = MFMA16(af1, bf, oacc[1][dt]);
            }
        }
    }

    // epilogue: O[b][s][h*64+d]
    #pragma unroll
    for (int mt = 0; mt < 2; ++mt) {
        const float invl = 1.0f / lst[mt];
        #pragma unroll
        for (int r = 0; r < 4; ++r) {
            const float ir = __shfl(invl, quad * 4 + r);
            const int row = qt * 128 + w * 32 + mt * 16 + quad * 4 + r;
            unsigned short* dst = &O[((size_t)b * S_LEN + row) * E_DIM + h * 64];
            #pragma unroll
            for (int dt = 0; dt < 4; ++dt)
                dst[dt * 16 + lq] = f2bf(oacc[mt][dt][r] * ir);
        }
    }
}

// ---------------------------------------------------------------------------
// Kernel 3: Y[m][f] = sum_e O[m][e]*Wc[f][e]. 64x128 tiles -> 512 blocks.
// Register prefetch of next K-chunk.
// ---------------------------------------------------------------------------
__global__ __launch_bounds__(256, 2) void outproj_kernel(
    const unsigned short* __restrict__ O, const float* __restrict__ Wc,
    float* __restrict__ Y)
{
    __shared__ short at[64 * 72];
    __shared__ short bt[128 * 72];
    const int tid = threadIdx.x;
    const int lane = tid & 63, w = tid >> 6;
    const int quad = lane >> 4, lq = lane & 15;
    const int m0 = (blockIdx.x >> 2) * 64;
    const int f0 = (blockIdx.x & 3) * 128;

    f32x4 acc[8];
    #pragma unroll
    for (int nt = 0; nt < 8; ++nt) acc[nt] = 0.f;

    // preload chunk 0
    u32x4 pa[2];
    f32x4 pw[8];
    #pragma unroll
    for (int i = 0; i < 2; ++i) {
        const int u = tid + (i << 8);
        pa[i] = *(const u32x4*)&O[(size_t)(m0 + (u >> 3)) * E_DIM + (u & 7) * 8];
    }
    #pragma unroll
    for (int i = 0; i < 8; ++i) {
        const int u = tid + (i << 8);
        pw[i] = *(const f32x4*)&Wc[(size_t)(f0 + (u >> 4)) * E_DIM + (u & 15) * 4];
    }

    for (int e0 = 0; e0 < E_DIM; e0 += 64) {
        __syncthreads();
        #pragma unroll
        for (int i = 0; i < 2; ++i) {
            const int u = tid + (i << 8);
            *(u32x4*)&at[(u >> 3) * 72 + (u & 7) * 8] = pa[i];
        }
        #pragma unroll
        for (int i = 0; i < 8; ++i) {
            const int u = tid + (i << 8);
            u16x4 pk = { f2bf(pw[i][0]), f2bf(pw[i][1]), f2bf(pw[i][2]), f2bf(pw[i][3]) };
            *(u16x4*)&bt[(u >> 4) * 72 + (u & 15) * 4] = pk;
        }
        __syncthreads();

        const int e1 = (e0 + 64 < E_DIM) ? e0 + 64 : 0;
        #pragma unroll
        for (int i = 0; i < 2; ++i) {
            const int u = tid + (i << 8);
            pa[i] = *(const u32x4*)&O[(size_t)(m0 + (u >> 3)) * E_DIM + e1 + (u & 7) * 8];
        }
        #pragma unroll
        for (int i = 0; i < 8; ++i) {
            const int u = tid + (i << 8);
            pw[i] = *(const f32x4*)&Wc[(size_t)(f0 + (u >> 4)) * E_DIM + e1 + (u & 15) * 4];
        }

        bf16x8 afk[2];
        #pragma unroll
        for (int ks = 0; ks < 2; ++ks)
            afk[ks] = *(const bf16x8*)&at[(w * 16 + lq) * 72 + ks * 32 + quad * 8];
        #pragma unroll
        for (int nt = 0; nt < 8; ++nt) {
            #pragma unroll
            for (int ks = 0; ks < 2; ++ks) {
                bf16x8 bf = *(const bf16x8*)&bt[(nt * 16 + lq) * 72 + ks * 32 + quad * 8];
                acc[nt] = MFMA16(afk[ks], bf, acc[nt]);
            }
        }
    }

    #pragma unroll
    for (int nt = 0; nt < 8; ++nt)
        #pragma unroll
        for (int r = 0; r < 4; ++r)
            Y[(size_t)(m0 + w * 16 + quad * 4 + r) * E_DIM + f0 + nt * 16 + lq] = acc[nt][r];
}

// ---------------------------------------------------------------------------
extern "C" void kernel_launch(void* const* d_in, const int* in_sizes, int n_in,
                              void* d_out, int out_size, void* d_ws, size_t ws_size,
                              hipStream_t stream) {
    const float* x     = (const float*)d_in[0];
    const float* theta = (const float*)d_in[1];
    const float* Wq    = (const float*)d_in[2];
    const float* Wk    = (const float*)d_in[3];
    const float* Wv    = (const float*)d_in[4];
    const float* Wc    = (const float*)d_in[5];
    float* Y = (float*)d_out;

    char* ws = (char*)d_ws;
    unsigned short* Q  = (unsigned short*)(ws);                      // 8 MB
    unsigned short* K  = (unsigned short*)(ws + ((size_t)8 << 20));  // 8 MB
    unsigned short* Vt = (unsigned short*)(ws + ((size_t)16 << 20)); // 8 MB
    unsigned short* O  = (unsigned short*)(ws + ((size_t)24 << 20)); // 8 MB

    qkv_kernel<<<(N_B * S_LEN / 32) * 3, 256, 0, stream>>>(x, theta, Wq, Wk, Wv, Q, K, Vt);
    flash_kernel<<<N_B * N_H * (S_LEN / 128), 256, 0, stream>>>(Q, K, Vt, O);
    outproj_kernel<<<(N_B * S_LEN / 64) * (E_DIM / 128), 256, 0, stream>>>(O, Wc, Y);
}

// Round 3
// 142.030 us; speedup vs baseline: 1.7551x; 1.0278x over previous
//
#include <hip/hip_runtime.h>
#include <stdint.h>

#define N_B 4
#define S_LEN 2048
#define N_H 8
#define E_DIM 512

typedef __attribute__((ext_vector_type(8))) short bf16x8;
typedef __attribute__((ext_vector_type(4))) float f32x4;
typedef __attribute__((ext_vector_type(4))) unsigned int u32x4;
typedef __attribute__((ext_vector_type(2))) unsigned int u32x2;
typedef __attribute__((ext_vector_type(4))) unsigned short u16x4;
typedef __attribute__((ext_vector_type(8))) unsigned short u16x8;

#define MFMA16(a, b, c) __builtin_amdgcn_mfma_f32_16x16x32_bf16((a), (b), (c), 0, 0, 0)

__device__ __forceinline__ unsigned short f2bf(float f) {
    union { float f; unsigned int u; } v; v.f = f;
    unsigned int r = v.u + 0x7fffu + ((v.u >> 16) & 1u);
    return (unsigned short)(r >> 16);
}

// pack two f32 -> two bf16 (round-half-up) in one u32 via v_perm
__device__ __forceinline__ unsigned int pack2bf(float lo, float hi) {
    union { float f; unsigned int u; } a, b; a.f = lo; b.f = hi;
    return __builtin_amdgcn_perm(b.u + 0x8000u, a.u + 0x8000u, 0x07060302u);
}

__device__ __forceinline__ float fexp2(float x) {
#if __has_builtin(__builtin_amdgcn_exp2f)
    return __builtin_amdgcn_exp2f(x);
#else
    return exp2f(x);
#endif
}

// Q pre-scale: 1/sqrt(64) * log2(e)  (scores land in log2 domain; fixed-max
// softmax is safe: |score_log2| <= ~60 << fp32 exponent range)
#define Q_SCALE 0.18033688f

// ---------------------------------------------------------------------------
// Kernel 1: proj = cos(x+theta); Q,K row-major [BH][S][64] bf16 (Q*Q_SCALE);
//           Vt [BH][64][S] bf16.  grid = 256 chunks x 3 mats = 768 blocks.
// Q/K path: thread owns 4 consecutive e-cols for 16 s-rows -> u16x4 stores.
// ---------------------------------------------------------------------------
__global__ __launch_bounds__(256) void qkv_kernel(
    const float* __restrict__ x, const float* __restrict__ theta,
    const float* __restrict__ Wq, const float* __restrict__ Wk,
    const float* __restrict__ Wv,
    unsigned short* __restrict__ Q, unsigned short* __restrict__ K,
    unsigned short* __restrict__ Vt)
{
    __shared__ float proj[32][8];
    const int tid = threadIdx.x;
    const int mat = blockIdx.x % 3;
    const int chunk = blockIdx.x / 3;
    const int row0 = chunk * 32;
    const int b = row0 >> 11;
    const int s_in_b = row0 & (S_LEN - 1);

    proj[tid >> 3][tid & 7] = cosf(x[row0 * 8 + tid] + theta[tid & 7]);
    __syncthreads();

    if (mat < 2) {
        const float* W = (mat == 0) ? Wq : Wk;
        const float scale = (mat == 0) ? Q_SCALE : 1.0f;
        unsigned short* outp = (mat == 0) ? Q : K;
        const int eg = (tid & 127) * 4;      // 4 consecutive e-columns
        const int sg = (tid >> 7) * 16;      // 16 s-rows
        float w[4][8];
        #pragma unroll
        for (int e = 0; e < 4; ++e)
            #pragma unroll
            for (int n = 0; n < 8; ++n)
                w[e][n] = W[(eg + e) * 8 + n] * scale;
        const int h = eg >> 6, d0 = eg & 63;
        unsigned short* p0 = outp + ((size_t)(b * N_H + h) * S_LEN + s_in_b + sg) * 64 + d0;
        #pragma unroll 4
        for (int s = 0; s < 16; ++s) {
            f32x4 pa = *(const f32x4*)&proj[sg + s][0];
            f32x4 pc = *(const f32x4*)&proj[sg + s][4];
            u16x4 o;
            #pragma unroll
            for (int e = 0; e < 4; ++e) {
                float a = 0.f;
                #pragma unroll
                for (int n = 0; n < 4; ++n)
                    a += pa[n] * w[e][n] + pc[n] * w[e][n + 4];
                o[e] = f2bf(a);
            }
            *(u16x4*)&p0[s * 64] = o;
        }
    } else {
        // Vt: 4 lanes per e-column; lane handles 8 s-values -> u16x8.
        f32x4 ps[8][2];
        const int sl0 = (tid & 3) * 8;
        #pragma unroll
        for (int k2 = 0; k2 < 8; ++k2) {
            ps[k2][0] = *(const f32x4*)&proj[sl0 + k2][0];
            ps[k2][1] = *(const f32x4*)&proj[sl0 + k2][4];
        }
        const int ecol = tid >> 2;   // 0..63
        for (int pass = 0; pass < 8; ++pass) {
            const int e = pass * 64 + ecol;
            const int h = e >> 6, dd = e & 63;
            float wr[8];
            #pragma unroll
            for (int n = 0; n < 8; ++n) wr[n] = Wv[e * 8 + n];
            u16x8 pk;
            #pragma unroll
            for (int k2 = 0; k2 < 8; ++k2) {
                float acc = 0.f;
                #pragma unroll
                for (int n = 0; n < 4; ++n)
                    acc += ps[k2][0][n] * wr[n] + ps[k2][1][n] * wr[n + 4];
                pk[k2] = f2bf(acc);
            }
            *(u16x8*)&Vt[((size_t)(b * N_H + h) * 64 + dd) * S_LEN + s_in_b + sl0] = pk;
        }
    }
}

// ---------------------------------------------------------------------------
// Kernel 2: flash attention, fixed-max (M=0) softmax. K-tile = 64 ->
// LDS 36.9 KB -> 4 blocks/CU. S^T = K.Q^T, per-lane row-sum deferred to
// epilogue. grid = 512 blocks, 256 threads.
// ---------------------------------------------------------------------------
__global__ __launch_bounds__(256, 4) void flash_kernel(
    const unsigned short* __restrict__ Q, const unsigned short* __restrict__ K,
    const unsigned short* __restrict__ Vt, unsigned short* __restrict__ O)
{
    __shared__ short kt[64 * 72];     // K-tile: [k=64][d=64]+pad
    __shared__ short vt[64 * 72];     // V-tile: [d=64][s=64]+pad
    __shared__ short pb[128 * 72];    // P: [qrow=128][k=64]+pad (wave-private rows)

    const int tid = threadIdx.x;
    const int lane = tid & 63, w = tid >> 6;
    const int quad = lane >> 4, lq = lane & 15;
    const int qt = blockIdx.x & 15, bh = blockIdx.x >> 4;
    const int b = bh >> 3, h = bh & 7;

    const unsigned short* Qb = Q + (size_t)bh * S_LEN * 64;
    const unsigned short* Kb = K + (size_t)bh * S_LEN * 64;
    const unsigned short* Vb = Vt + (size_t)bh * 64 * S_LEN;

    // Q fragments (MFMA B-operand): lane holds Q[q=lq][d=quad*8+j]
    bf16x8 qf[2][2];
    #pragma unroll
    for (int mt = 0; mt < 2; ++mt)
        #pragma unroll
        for (int ks = 0; ks < 2; ++ks)
            qf[mt][ks] = *(const bf16x8*)&Qb[(size_t)(qt * 128 + w * 32 + mt * 16 + lq) * 64 + ks * 32 + quad * 8];

    f32x4 oacc[2][4];
    #pragma unroll
    for (int mt = 0; mt < 2; ++mt)
        #pragma unroll
        for (int dt = 0; dt < 4; ++dt) oacc[mt][dt] = 0.f;
    float lsum[2] = {0.f, 0.f};

    // preload tile 0
    u32x4 pkr[2], pvr[2];
    #pragma unroll
    for (int i = 0; i < 2; ++i) {
        const int u = tid + (i << 8);
        pkr[i] = *(const u32x4*)&Kb[(size_t)(u >> 3) * 64 + (u & 7) * 8];
        pvr[i] = *(const u32x4*)&Vb[(size_t)(u >> 3) * S_LEN + (u & 7) * 8];
    }

    for (int kti = 0; kti < 32; ++kti) {
        __syncthreads();   // prior tile's LDS reads complete
        #pragma unroll
        for (int i = 0; i < 2; ++i) {
            const int u = tid + (i << 8);
            *(u32x4*)&kt[(u >> 3) * 72 + (u & 7) * 8] = pkr[i];
            *(u32x4*)&vt[(u >> 3) * 72 + (u & 7) * 8] = pvr[i];
        }
        __syncthreads();

        // prefetch next tile (dummy tile 0 on last iter)
        const int kb2 = (kti < 31) ? (kti + 1) * 64 : 0;
        #pragma unroll
        for (int i = 0; i < 2; ++i) {
            const int u = tid + (i << 8);
            pkr[i] = *(const u32x4*)&Kb[(size_t)(kb2 + (u >> 3)) * 64 + (u & 7) * 8];
            pvr[i] = *(const u32x4*)&Vb[(size_t)(u >> 3) * S_LEN + kb2 + (u & 7) * 8];
        }

        // S^T = K . Q^T : lane (quad,lq) elem r -> S^T[k=mts*16+quad*4+r][q=lq]
        f32x4 sacc[2][4];
        #pragma unroll
        for (int mt = 0; mt < 2; ++mt)
            #pragma unroll
            for (int mts = 0; mts < 4; ++mts) sacc[mt][mts] = 0.f;
        #pragma unroll
        for (int mts = 0; mts < 4; ++mts) {
            #pragma unroll
            for (int ks = 0; ks < 2; ++ks) {
                bf16x8 af = *(const bf16x8*)&kt[(mts * 16 + lq) * 72 + ks * 32 + quad * 8];
                sacc[0][mts] = MFMA16(af, qf[0][ks], sacc[0][mts]);
                sacc[1][mts] = MFMA16(af, qf[1][ks], sacc[1][mts]);
            }
        }

        // fixed-max softmax: p = exp2(s); accumulate row-sum per lane; write P.
        #pragma unroll
        for (int mt = 0; mt < 2; ++mt) {
            #pragma unroll
            for (int mts = 0; mts < 4; ++mts) {
                f32x4 p;
                #pragma unroll
                for (int e = 0; e < 4; ++e) p[e] = fexp2(sacc[mt][mts][e]);
                lsum[mt] += (p[0] + p[1]) + (p[2] + p[3]);
                u32x2 pw = { pack2bf(p[0], p[1]), pack2bf(p[2], p[3]) };
                *(u32x2*)&pb[(w * 32 + mt * 16 + lq) * 72 + mts * 16 + quad * 4] = pw;
            }
        }
        // pb rows are wave-private: no barrier between write and read.

        // O += P . V
        #pragma unroll
        for (int ks = 0; ks < 2; ++ks) {
            bf16x8 af0 = *(const bf16x8*)&pb[(w * 32 + lq) * 72 + ks * 32 + quad * 8];
            bf16x8 af1 = *(const bf16x8*)&pb[(w * 32 + 16 + lq) * 72 + ks * 32 + quad * 8];
            #pragma unroll
            for (int dt = 0; dt < 4; ++dt) {
                bf16x8 bf = *(const bf16x8*)&vt[(dt * 16 + lq) * 72 + ks * 32 + quad * 8];
                oacc[0][dt] = MFMA16(af0, bf, oacc[0][dt]);
                oacc[1][dt] = MFMA16(af1, bf, oacc[1][dt]);
            }
        }
    }

    // epilogue: reduce row-sums across quads, normalize, store O[b][s][h*64+d]
    #pragma unroll
    for (int mt = 0; mt < 2; ++mt) {
        float rs = lsum[mt];
        rs += __shfl_xor(rs, 16);
        rs += __shfl_xor(rs, 32);
        const float inv = 1.0f / rs;
        #pragma unroll
        for (int r = 0; r < 4; ++r) {
            const float ir = __shfl(inv, quad * 4 + r);
            const int row = qt * 128 + w * 32 + mt * 16 + quad * 4 + r;
            unsigned short* dst = &O[((size_t)b * S_LEN + row) * E_DIM + h * 64];
            #pragma unroll
            for (int dt = 0; dt < 4; ++dt)
                dst[dt * 16 + lq] = f2bf(oacc[mt][dt][r] * ir);
        }
    }
}

// ---------------------------------------------------------------------------
// Kernel 3: Y[m][f] = sum_e O[m][e]*Wc[f][e]. 64x64 tiles -> 1024 blocks
// (4 blocks/CU). Register prefetch of next K-chunk.
// ---------------------------------------------------------------------------
__global__ __launch_bounds__(256, 4) void outproj_kernel(
    const unsigned short* __restrict__ O, const float* __restrict__ Wc,
    float* __restrict__ Y)
{
    __shared__ short at[64 * 72];
    __shared__ short bt[64 * 72];
    const int tid = threadIdx.x;
    const int lane = tid & 63, w = tid >> 6;
    const int quad = lane >> 4, lq = lane & 15;
    const int m0 = (blockIdx.x >> 3) * 64;
    const int f0 = (blockIdx.x & 7) * 64;

    f32x4 acc[4];
    #pragma unroll
    for (int nt = 0; nt < 4; ++nt) acc[nt] = 0.f;

    // preload chunk 0
    u32x4 pa[2];
    f32x4 pw[4];
    #pragma unroll
    for (int i = 0; i < 2; ++i) {
        const int u = tid + (i << 8);
        pa[i] = *(const u32x4*)&O[(size_t)(m0 + (u >> 3)) * E_DIM + (u & 7) * 8];
    }
    #pragma unroll
    for (int i = 0; i < 4; ++i) {
        const int u = tid + (i << 8);
        pw[i] = *(const f32x4*)&Wc[(size_t)(f0 + (u >> 4)) * E_DIM + (u & 15) * 4];
    }

    for (int e0 = 0; e0 < E_DIM; e0 += 64) {
        __syncthreads();
        #pragma unroll
        for (int i = 0; i < 2; ++i) {
            const int u = tid + (i << 8);
            *(u32x4*)&at[(u >> 3) * 72 + (u & 7) * 8] = pa[i];
        }
        #pragma unroll
        for (int i = 0; i < 4; ++i) {
            const int u = tid + (i << 8);
            u16x4 pk = { f2bf(pw[i][0]), f2bf(pw[i][1]), f2bf(pw[i][2]), f2bf(pw[i][3]) };
            *(u16x4*)&bt[(u >> 4) * 72 + (u & 15) * 4] = pk;
        }
        __syncthreads();

        const int e1 = (e0 + 64 < E_DIM) ? e0 + 64 : 0;
        #pragma unroll
        for (int i = 0; i < 2; ++i) {
            const int u = tid + (i << 8);
            pa[i] = *(const u32x4*)&O[(size_t)(m0 + (u >> 3)) * E_DIM + e1 + (u & 7) * 8];
        }
        #pragma unroll
        for (int i = 0; i < 4; ++i) {
            const int u = tid + (i << 8);
            pw[i] = *(const f32x4*)&Wc[(size_t)(f0 + (u >> 4)) * E_DIM + e1 + (u & 15) * 4];
        }

        bf16x8 afk[2];
        #pragma unroll
        for (int ks = 0; ks < 2; ++ks)
            afk[ks] = *(const bf16x8*)&at[(w * 16 + lq) * 72 + ks * 32 + quad * 8];
        #pragma unroll
        for (int nt = 0; nt < 4; ++nt) {
            #pragma unroll
            for (int ks = 0; ks < 2; ++ks) {
                bf16x8 bf = *(const bf16x8*)&bt[(nt * 16 + lq) * 72 + ks * 32 + quad * 8];
                acc[nt] = MFMA16(afk[ks], bf, acc[nt]);
            }
        }
    }

    #pragma unroll
    for (int nt = 0; nt < 4; ++nt)
        #pragma unroll
        for (int r = 0; r < 4; ++r)
            Y[(size_t)(m0 + w * 16 + quad * 4 + r) * E_DIM + f0 + nt * 16 + lq] = acc[nt][r];
}

// ---------------------------------------------------------------------------
extern "C" void kernel_launch(void* const* d_in, const int* in_sizes, int n_in,
                              void* d_out, int out_size, void* d_ws, size_t ws_size,
                              hipStream_t stream) {
    const float* x     = (const float*)d_in[0];
    const float* theta = (const float*)d_in[1];
    const float* Wq    = (const float*)d_in[2];
    const float* Wk    = (const float*)d_in[3];
    const float* Wv    = (const float*)d_in[4];
    const float* Wc    = (const float*)d_in[5];
    float* Y = (float*)d_out;

    char* ws = (char*)d_ws;
    unsigned short* Q  = (unsigned short*)(ws);                      // 8 MB
    unsigned short* K  = (unsigned short*)(ws + ((size_t)8 << 20));  // 8 MB
    unsigned short* Vt = (unsigned short*)(ws + ((size_t)16 << 20)); // 8 MB
    unsigned short* O  = (unsigned short*)(ws + ((size_t)24 << 20)); // 8 MB

    qkv_kernel<<<(N_B * S_LEN / 32) * 3, 256, 0, stream>>>(x, theta, Wq, Wk, Wv, Q, K, Vt);
    flash_kernel<<<N_B * N_H * (S_LEN / 128), 256, 0, stream>>>(Q, K, Vt, O);
    outproj_kernel<<<(N_B * S_LEN / 64) * (E_DIM / 64), 256, 0, stream>>>(O, Wc, Y);
}